// Round 3
// baseline (267.491 us; speedup 1.0000x reference)
//
#include <hip/hip_runtime.h>
#include <hip/hip_bf16.h>
#include <math.h>

#define NN 50000
#define NE 1000000
#define FIN 128
#define FOUT 64
#define NEG 0.2f

// Kernel 1: Wh = x @ W  [N,64] (stored bf16 for the gather), fused
// s_src = Wh·a_src, s_dst = Wh·a_dst (computed in fp32 before conversion).
// lane = output feature; 4 nodes per wave-iteration; x row loads are
// wave-uniform (scalar path), W staged in LDS.
__global__ __launch_bounds__(256) void k_gemm(
    const float* __restrict__ x, const float* __restrict__ W,
    const float* __restrict__ a_src, const float* __restrict__ a_dst,
    __hip_bfloat16* __restrict__ Whb, float* __restrict__ s_src,
    float* __restrict__ s_dst)
{
    __shared__ float Wl[FIN * FOUT];   // 32 KB
    for (int i = threadIdx.x; i < FIN * FOUT; i += 256) Wl[i] = W[i];
    __syncthreads();

    const int lane = threadIdx.x & 63;
    const int wave = threadIdx.x >> 6;
    const float asv = a_src[lane];
    const float adv = a_dst[lane];

    const int ngroups = NN / 4;        // 12500, exact
    for (int g = blockIdx.x * 4 + wave; g < ngroups; g += gridDim.x * 4) {
        const int gu = __builtin_amdgcn_readfirstlane(g);
        const float* xr = x + (size_t)gu * (4 * FIN);
        float a0 = 0.f, a1 = 0.f, a2 = 0.f, a3 = 0.f;
        #pragma unroll 8
        for (int k = 0; k < FIN; ++k) {
            const float wv = Wl[k * FOUT + lane];
            a0 = fmaf(xr[k],           wv, a0);
            a1 = fmaf(xr[FIN + k],     wv, a1);
            a2 = fmaf(xr[2 * FIN + k], wv, a2);
            a3 = fmaf(xr[3 * FIN + k], wv, a3);
        }
        const int n0 = gu * 4;
        Whb[(size_t)n0 * FOUT + lane]       = __float2bfloat16(a0);
        Whb[(size_t)(n0 + 1) * FOUT + lane] = __float2bfloat16(a1);
        Whb[(size_t)(n0 + 2) * FOUT + lane] = __float2bfloat16(a2);
        Whb[(size_t)(n0 + 3) * FOUT + lane] = __float2bfloat16(a3);

        float r0s = a0 * asv, r0d = a0 * adv;
        float r1s = a1 * asv, r1d = a1 * adv;
        float r2s = a2 * asv, r2d = a2 * adv;
        float r3s = a3 * asv, r3d = a3 * adv;
        #pragma unroll
        for (int off = 32; off; off >>= 1) {
            r0s += __shfl_xor(r0s, off); r0d += __shfl_xor(r0d, off);
            r1s += __shfl_xor(r1s, off); r1d += __shfl_xor(r1d, off);
            r2s += __shfl_xor(r2s, off); r2d += __shfl_xor(r2d, off);
            r3s += __shfl_xor(r3s, off); r3d += __shfl_xor(r3d, off);
        }
        if (lane == 0) {
            s_src[n0]     = r0s; s_dst[n0]     = r0d;
            s_src[n0 + 1] = r1s; s_dst[n0 + 1] = r1d;
            s_src[n0 + 2] = r2s; s_dst[n0 + 2] = r2d;
            s_src[n0 + 3] = r3s; s_dst[n0 + 3] = r3d;
        }
    }
}

// Kernel 2: in-degree histogram.
__global__ __launch_bounds__(256) void k_hist(
    const int* __restrict__ ei, int* __restrict__ counts)
{
    const int e = blockIdx.x * 256 + threadIdx.x;
    if (e < NE) atomicAdd(&counts[ei[NE + e]], 1);
}

// Kernel 3: single-block exclusive scan of counts[0..NN) -> offsets[0..NN],
// duplicate into cursor[]. 1024 threads, 8 items/thread/iter.
__global__ __launch_bounds__(1024) void k_scan(
    const int* __restrict__ counts, int* __restrict__ offsets,
    int* __restrict__ cursor)
{
    __shared__ int wsum[16];
    const int tid = threadIdx.x;
    const int lane = tid & 63;
    const int wv = tid >> 6;
    int running = 0;

    for (int base = 0; base < NN; base += 1024 * 8) {
        const int i0 = base + tid * 8;
        int v[8];
        int s = 0;
        #pragma unroll
        for (int j = 0; j < 8; ++j) {
            const int idx = i0 + j;
            v[j] = (idx < NN) ? counts[idx] : 0;
            s += v[j];
        }
        int sc = s;
        #pragma unroll
        for (int off = 1; off < 64; off <<= 1) {
            const int t = __shfl_up(sc, off);
            if (lane >= off) sc += t;
        }
        if (lane == 63) wsum[wv] = sc;
        __syncthreads();
        if (wv == 0 && lane < 16) {
            int w = wsum[lane];
            #pragma unroll
            for (int off = 1; off < 16; off <<= 1) {
                const int t = __shfl_up(w, off);
                if (lane >= off) w += t;
            }
            wsum[lane] = w;
        }
        __syncthreads();
        const int block_prefix = (wv > 0) ? wsum[wv - 1] : 0;
        int excl = running + block_prefix + (sc - s);
        #pragma unroll
        for (int j = 0; j < 8; ++j) {
            const int idx = i0 + j;
            if (idx < NN) { offsets[idx] = excl; cursor[idx] = excl; }
            excl += v[j];
        }
        const int total = wsum[15];
        __syncthreads();
        running += total;
    }
    if (tid == 0) offsets[NN] = running;   // == NE
}

// Kernel 4: CSR fill — src index only (ev recomputed in gather). Single 4B
// scattered store per edge (half the sectored HBM writes of src+ev).
__global__ __launch_bounds__(256) void k_fill(
    const int* __restrict__ ei, int* __restrict__ cursor,
    int* __restrict__ csr_src)
{
    const int e = blockIdx.x * 256 + threadIdx.x;
    if (e >= NE) return;
    const int s = ei[e];
    const int d = ei[NE + e];
    const int pos = atomicAdd(&cursor[d], 1);
    csr_src[pos] = s;
}

// Kernel 5: gather per dst node. One wave per node, lane = feature.
// Recomputes ev = exp(lrelu(s_src[s] + s_dst[n])) (same fp32 math as the
// reference path; global-max stabilizer cancels in e/denom). Fuses denom,
// normalization, ELU. No atomics.
__global__ __launch_bounds__(256) void k_gather(
    const int* __restrict__ offsets, const int* __restrict__ csr_src,
    const float* __restrict__ s_src, const float* __restrict__ s_dst,
    const __hip_bfloat16* __restrict__ Whb, float* __restrict__ out)
{
    const int n = blockIdx.x * 4 + (threadIdx.x >> 6);   // 12500 blocks, exact
    const int lane = threadIdx.x & 63;
    const int beg = offsets[n];
    const int end = offsets[n + 1];
    const float sd = s_dst[n];

    float acc = 0.f, den = 0.f;
    int i = beg;
    for (; i + 4 <= end; i += 4) {
        const int s0 = csr_src[i];
        const int s1 = csr_src[i + 1];
        const int s2 = csr_src[i + 2];
        const int s3 = csr_src[i + 3];
        float v0 = s_src[s0] + sd; v0 = (v0 > 0.f) ? v0 : NEG * v0;
        float v1 = s_src[s1] + sd; v1 = (v1 > 0.f) ? v1 : NEG * v1;
        float v2 = s_src[s2] + sd; v2 = (v2 > 0.f) ? v2 : NEG * v2;
        float v3 = s_src[s3] + sd; v3 = (v3 > 0.f) ? v3 : NEG * v3;
        const float e0 = __expf(v0);
        const float e1 = __expf(v1);
        const float e2 = __expf(v2);
        const float e3 = __expf(v3);
        acc = fmaf(e0, __bfloat162float(Whb[(size_t)s0 * FOUT + lane]), acc);
        acc = fmaf(e1, __bfloat162float(Whb[(size_t)s1 * FOUT + lane]), acc);
        acc = fmaf(e2, __bfloat162float(Whb[(size_t)s2 * FOUT + lane]), acc);
        acc = fmaf(e3, __bfloat162float(Whb[(size_t)s3 * FOUT + lane]), acc);
        den += (e0 + e1) + (e2 + e3);
    }
    for (; i < end; ++i) {
        const int s0 = csr_src[i];
        float v0 = s_src[s0] + sd; v0 = (v0 > 0.f) ? v0 : NEG * v0;
        const float e0 = __expf(v0);
        acc = fmaf(e0, __bfloat162float(Whb[(size_t)s0 * FOUT + lane]), acc);
        den += e0;
    }
    const float r = acc / (den + 1e-16f);
    out[(size_t)n * FOUT + lane] = (r > 0.f) ? r : expm1f(r);
}

extern "C" void kernel_launch(void* const* d_in, const int* in_sizes, int n_in,
                              void* d_out, int out_size, void* d_ws, size_t ws_size,
                              hipStream_t stream)
{
    const float* x     = (const float*)d_in[0];
    const int*   ei    = (const int*)d_in[1];   // [2,E]: src = ei[0..E), dst = ei[E..2E)
    const float* W     = (const float*)d_in[2];
    const float* a_src = (const float*)d_in[3];
    const float* a_dst = (const float*)d_in[4];
    float* out = (float*)d_out;

    // Workspace layout (4B elems):
    // Whb[N*64 bf16 = N*32 floats] | s_src[N] | s_dst[N] | counts[N] |
    // offsets[N+1] | cursor[N] | csr_src[E]
    float* ws      = (float*)d_ws;
    __hip_bfloat16* Whb = (__hip_bfloat16*)ws;
    float* s_src   = ws + (size_t)NN * FOUT / 2;
    float* s_dst   = s_src + NN;
    int*   counts  = (int*)(s_dst + NN);
    int*   offsets = counts + NN;
    int*   cursor  = offsets + (NN + 1);
    int*   csr_src = cursor + NN;

    hipMemsetAsync(counts, 0, NN * sizeof(int), stream);

    k_gemm<<<1024, 256, 0, stream>>>(x, W, a_src, a_dst, Whb, s_src, s_dst);
    k_hist<<<(NE + 255) / 256, 256, 0, stream>>>(ei, counts);
    k_scan<<<1, 1024, 0, stream>>>(counts, offsets, cursor);
    k_fill<<<(NE + 255) / 256, 256, 0, stream>>>(ei, cursor, csr_src);
    k_gather<<<NN / 4, 256, 0, stream>>>(offsets, csr_src, s_src, s_dst, Whb, out);
}

// Round 4
// 216.473 us; speedup vs baseline: 1.2357x; 1.2357x over previous
//
#include <hip/hip_runtime.h>
#include <hip/hip_bf16.h>
#include <math.h>

#define NN 50000
#define NE 1000000
#define FIN 128
#define FOUT 64
#define NEG 0.2f

#define NB   1024   // dst-range buckets (1021 used: ceil(50000/49))
#define DPB  49     // dsts per bucket
#define CAPB 256    // capacity per (slot,bucket); mean load ~122, sigma ~11
#define NBUSED 1021

// Kernel 1: Wh = x @ W [N,64] (stored bf16), fused s_src = Wh·a_src,
// s_dst = Wh·a_dst (fp32). lane = feature; 4 nodes per wave-iteration;
// x rows are wave-uniform loads; W staged in LDS.
__global__ __launch_bounds__(256) void k_gemm(
    const float* __restrict__ x, const float* __restrict__ W,
    const float* __restrict__ a_src, const float* __restrict__ a_dst,
    __hip_bfloat16* __restrict__ Whb, float* __restrict__ s_src,
    float* __restrict__ s_dst)
{
    __shared__ float Wl[FIN * FOUT];   // 32 KB
    for (int i = threadIdx.x; i < FIN * FOUT; i += 256) Wl[i] = W[i];
    __syncthreads();

    const int lane = threadIdx.x & 63;
    const int wave = threadIdx.x >> 6;
    const float asv = a_src[lane];
    const float adv = a_dst[lane];

    const int ngroups = NN / 4;        // 12500, exact
    for (int g = blockIdx.x * 4 + wave; g < ngroups; g += gridDim.x * 4) {
        const int gu = __builtin_amdgcn_readfirstlane(g);
        const float* xr = x + (size_t)gu * (4 * FIN);
        float a0 = 0.f, a1 = 0.f, a2 = 0.f, a3 = 0.f;
        #pragma unroll 8
        for (int k = 0; k < FIN; ++k) {
            const float wv = Wl[k * FOUT + lane];
            a0 = fmaf(xr[k],           wv, a0);
            a1 = fmaf(xr[FIN + k],     wv, a1);
            a2 = fmaf(xr[2 * FIN + k], wv, a2);
            a3 = fmaf(xr[3 * FIN + k], wv, a3);
        }
        const int n0 = gu * 4;
        Whb[(size_t)n0 * FOUT + lane]       = __float2bfloat16(a0);
        Whb[(size_t)(n0 + 1) * FOUT + lane] = __float2bfloat16(a1);
        Whb[(size_t)(n0 + 2) * FOUT + lane] = __float2bfloat16(a2);
        Whb[(size_t)(n0 + 3) * FOUT + lane] = __float2bfloat16(a3);

        float r0s = a0 * asv, r0d = a0 * adv;
        float r1s = a1 * asv, r1d = a1 * adv;
        float r2s = a2 * asv, r2d = a2 * adv;
        float r3s = a3 * asv, r3d = a3 * adv;
        #pragma unroll
        for (int off = 32; off; off >>= 1) {
            r0s += __shfl_xor(r0s, off); r0d += __shfl_xor(r0d, off);
            r1s += __shfl_xor(r1s, off); r1d += __shfl_xor(r1d, off);
            r2s += __shfl_xor(r2s, off); r2d += __shfl_xor(r2d, off);
            r3s += __shfl_xor(r3s, off); r3d += __shfl_xor(r3d, off);
        }
        if (lane == 0) {
            s_src[n0]     = r0s; s_dst[n0]     = r0d;
            s_src[n0 + 1] = r1s; s_dst[n0 + 1] = r1d;
            s_src[n0 + 2] = r2s; s_dst[n0 + 2] = r2d;
            s_src[n0 + 3] = r3s; s_dst[n0 + 3] = r3d;
        }
    }
}

// Kernel 2: bucket append. packed = (src<<16)|dst; bucket = dst/49; slot =
// blockIdx&7 (XCD-local under default round-robin dispatch -> a given append
// stream is written by one XCD, so L2 lines fill before writeback).
__global__ __launch_bounds__(256) void k_bucket(
    const int* __restrict__ ei, int* __restrict__ bcur,
    int* __restrict__ bdata)
{
    const int e = blockIdx.x * 256 + threadIdx.x;
    if (e >= NE) return;
    const int s = ei[e];
    const int d = ei[NE + e];
    const int b = d / DPB;                 // constant div -> magic mul
    const int q = (blockIdx.x & 7) * NB + b;
    const int pos = atomicAdd(&bcur[q], 1);
    if (pos < CAPB) bdata[(q << 8) + pos] = (s << 16) | d;
}

// Kernel 3: per-bucket LDS counting-sort by dst + fused gather/normalize/ELU.
// One workgroup per bucket (49 dsts, ~980 edges). All scatter is in LDS.
__global__ __launch_bounds__(256) void k_sortgather(
    const int* __restrict__ bcur, const int* __restrict__ bdata,
    const float* __restrict__ s_src, const float* __restrict__ s_dst,
    const __hip_bfloat16* __restrict__ Whb, float* __restrict__ out)
{
    __shared__ int raw[8 * CAPB];      // 8 KB
    __shared__ int srt[8 * CAPB];      // 8 KB
    __shared__ int cnt[64];
    __shared__ int ofs[65];
    __shared__ int cur[64];

    const int b = blockIdx.x;
    const int tid = threadIdx.x;
    const int d0 = b * DPB;
    const int nd = (NN - d0 < DPB) ? (NN - d0) : DPB;

    if (tid < 64) cnt[tid] = 0;

    // segment lengths + prefix (redundant per-thread; broadcast loads)
    int len[8], seg[8];
    int tot = 0;
    #pragma unroll
    for (int xx = 0; xx < 8; ++xx) {
        int l = bcur[xx * NB + b];
        l = (l < CAPB) ? l : CAPB;
        len[xx] = l; seg[xx] = tot; tot += l;
    }

    // stage bucket edges into LDS (coalesced)
    #pragma unroll
    for (int xx = 0; xx < 8; ++xx) {
        const int* srcp = bdata + ((xx * NB + b) << 8);
        for (int i = tid; i < len[xx]; i += 256) raw[seg[xx] + i] = srcp[i];
    }
    __syncthreads();

    // count by dst (LDS atomics)
    for (int i = tid; i < tot; i += 256)
        atomicAdd(&cnt[(raw[i] & 0xffff) - d0], 1);
    __syncthreads();

    // exclusive scan over 49 counts (wave 0)
    if (tid < 64) {
        const int c = (tid < nd) ? cnt[tid] : 0;
        int inc = c;
        #pragma unroll
        for (int off = 1; off < 64; off <<= 1) {
            const int t = __shfl_up(inc, off);
            if (tid >= off) inc += t;
        }
        ofs[tid + 1] = inc;
        if (tid == 0) ofs[0] = 0;
        cur[tid] = inc - c;
    }
    __syncthreads();

    // scatter into sorted order (LDS scatter)
    for (int i = tid; i < tot; i += 256) {
        const int p = raw[i];
        const int j = (p & 0xffff) - d0;
        const int pos = atomicAdd(&cur[j], 1);
        srt[pos] = p;
    }
    __syncthreads();

    // gather: wave = dst, lane = feature
    const int lane = tid & 63;
    const int wv = tid >> 6;
    for (int j = wv; j < nd; j += 4) {
        const int d = d0 + j;
        const float sd = s_dst[d];
        const int beg = ofs[j];
        const int end = ofs[j + 1];
        float acc = 0.f, den = 0.f;
        int i = beg;
        for (; i + 4 <= end; i += 4) {
            const unsigned p0 = (unsigned)srt[i];
            const unsigned p1 = (unsigned)srt[i + 1];
            const unsigned p2 = (unsigned)srt[i + 2];
            const unsigned p3 = (unsigned)srt[i + 3];
            const int s0 = p0 >> 16, s1 = p1 >> 16, s2 = p2 >> 16, s3 = p3 >> 16;
            float v0 = s_src[s0] + sd; v0 = (v0 > 0.f) ? v0 : NEG * v0;
            float v1 = s_src[s1] + sd; v1 = (v1 > 0.f) ? v1 : NEG * v1;
            float v2 = s_src[s2] + sd; v2 = (v2 > 0.f) ? v2 : NEG * v2;
            float v3 = s_src[s3] + sd; v3 = (v3 > 0.f) ? v3 : NEG * v3;
            const float e0 = __expf(v0);
            const float e1 = __expf(v1);
            const float e2 = __expf(v2);
            const float e3 = __expf(v3);
            acc = fmaf(e0, __bfloat162float(Whb[(size_t)s0 * FOUT + lane]), acc);
            acc = fmaf(e1, __bfloat162float(Whb[(size_t)s1 * FOUT + lane]), acc);
            acc = fmaf(e2, __bfloat162float(Whb[(size_t)s2 * FOUT + lane]), acc);
            acc = fmaf(e3, __bfloat162float(Whb[(size_t)s3 * FOUT + lane]), acc);
            den += (e0 + e1) + (e2 + e3);
        }
        for (; i < end; ++i) {
            const unsigned p0 = (unsigned)srt[i];
            const int s0 = p0 >> 16;
            float v0 = s_src[s0] + sd; v0 = (v0 > 0.f) ? v0 : NEG * v0;
            const float e0 = __expf(v0);
            acc = fmaf(e0, __bfloat162float(Whb[(size_t)s0 * FOUT + lane]), acc);
            den += e0;
        }
        const float r = acc / (den + 1e-16f);
        out[(size_t)d * FOUT + lane] = (r > 0.f) ? r : expm1f(r);
    }
}

extern "C" void kernel_launch(void* const* d_in, const int* in_sizes, int n_in,
                              void* d_out, int out_size, void* d_ws, size_t ws_size,
                              hipStream_t stream)
{
    const float* x     = (const float*)d_in[0];
    const int*   ei    = (const int*)d_in[1];   // [2,E]: src = ei[0..E), dst = ei[E..2E)
    const float* W     = (const float*)d_in[2];
    const float* a_src = (const float*)d_in[3];
    const float* a_dst = (const float*)d_in[4];
    float* out = (float*)d_out;

    // Workspace (bytes): Whb 6.4 MB | s_src 200 KB | s_dst 200 KB |
    // bcur 32 KB | bdata 8 MB  -> ~14.9 MB
    float* ws    = (float*)d_ws;
    __hip_bfloat16* Whb = (__hip_bfloat16*)ws;
    float* s_src = ws + (size_t)NN * FOUT / 2;
    float* s_dst = s_src + NN;
    int*   bcur  = (int*)(s_dst + NN);
    int*   bdata = bcur + 8 * NB;

    hipMemsetAsync(bcur, 0, 8 * NB * sizeof(int), stream);

    k_gemm<<<1024, 256, 0, stream>>>(x, W, a_src, a_dst, Whb, s_src, s_dst);
    k_bucket<<<(NE + 255) / 256, 256, 0, stream>>>(ei, bcur, bdata);
    k_sortgather<<<NBUSED, 256, 0, stream>>>(bcur, bdata, s_src, s_dst, Whb, out);
}

// Round 5
// 161.269 us; speedup vs baseline: 1.6587x; 1.3423x over previous
//
#include <hip/hip_runtime.h>
#include <hip/hip_bf16.h>
#include <math.h>

#define NN 50000
#define NE 1000000
#define FIN 128
#define FOUT 64
#define NEG 0.2f

#define NB   1024     // dst-range buckets (1021 used)
#define DPB  49       // dsts per bucket
#define NBUSED 1021
#define TS   4096     // edges per sort tile
#define NT   245      // 244 full tiles + 576-edge tail

// Kernel 1: Wh = x @ W [N,64] (stored bf16), fused s_src/s_dst.
// W staged TRANSPOSED in LDS as float4 rows (padded to 33) so each lane
// fetches 4 k-values per ds_read_b128 (4x fewer LDS instrs than b32/k).
// x rows are wave-uniform (scalar-load path); lane = output feature.
__global__ __launch_bounds__(256) void k_gemm(
    const float* __restrict__ x, const float* __restrict__ W,
    const float* __restrict__ a_src, const float* __restrict__ a_dst,
    __hip_bfloat16* __restrict__ Whb, float* __restrict__ s_src,
    float* __restrict__ s_dst)
{
    __shared__ float4 Wv[FOUT][33];    // Wv[f][kc] = W[4kc..4kc+3][f]; ~33.8 KB
    for (int i = threadIdx.x; i < FIN * FOUT; i += 256) {
        const int k = i >> 6, f = i & 63;
        ((float*)&Wv[f][0])[k] = W[i];
    }
    __syncthreads();

    const int lane = threadIdx.x & 63;
    const int wave = threadIdx.x >> 6;
    const float asv = a_src[lane];
    const float adv = a_dst[lane];

    const int ngroups = NN / 4;        // 12500, exact
    for (int g = blockIdx.x * 4 + wave; g < ngroups; g += gridDim.x * 4) {
        const int gu = __builtin_amdgcn_readfirstlane(g);
        const float* xr = x + (size_t)gu * (4 * FIN);
        float a0 = 0.f, a1 = 0.f, a2 = 0.f, a3 = 0.f;
        #pragma unroll 4
        for (int kc = 0; kc < FIN / 4; ++kc) {
            const float4 w4 = Wv[lane][kc];
            const int k = 4 * kc;
            a0 = fmaf(xr[k],     w4.x, a0);
            a0 = fmaf(xr[k + 1], w4.y, a0);
            a0 = fmaf(xr[k + 2], w4.z, a0);
            a0 = fmaf(xr[k + 3], w4.w, a0);
            a1 = fmaf(xr[FIN + k],     w4.x, a1);
            a1 = fmaf(xr[FIN + k + 1], w4.y, a1);
            a1 = fmaf(xr[FIN + k + 2], w4.z, a1);
            a1 = fmaf(xr[FIN + k + 3], w4.w, a1);
            a2 = fmaf(xr[2 * FIN + k],     w4.x, a2);
            a2 = fmaf(xr[2 * FIN + k + 1], w4.y, a2);
            a2 = fmaf(xr[2 * FIN + k + 2], w4.z, a2);
            a2 = fmaf(xr[2 * FIN + k + 3], w4.w, a2);
            a3 = fmaf(xr[3 * FIN + k],     w4.x, a3);
            a3 = fmaf(xr[3 * FIN + k + 1], w4.y, a3);
            a3 = fmaf(xr[3 * FIN + k + 2], w4.z, a3);
            a3 = fmaf(xr[3 * FIN + k + 3], w4.w, a3);
        }
        const int n0 = gu * 4;
        Whb[(size_t)n0 * FOUT + lane]       = __float2bfloat16(a0);
        Whb[(size_t)(n0 + 1) * FOUT + lane] = __float2bfloat16(a1);
        Whb[(size_t)(n0 + 2) * FOUT + lane] = __float2bfloat16(a2);
        Whb[(size_t)(n0 + 3) * FOUT + lane] = __float2bfloat16(a3);

        float r0s = a0 * asv, r0d = a0 * adv;
        float r1s = a1 * asv, r1d = a1 * adv;
        float r2s = a2 * asv, r2d = a2 * adv;
        float r3s = a3 * asv, r3d = a3 * adv;
        #pragma unroll
        for (int off = 32; off; off >>= 1) {
            r0s += __shfl_xor(r0s, off); r0d += __shfl_xor(r0d, off);
            r1s += __shfl_xor(r1s, off); r1d += __shfl_xor(r1d, off);
            r2s += __shfl_xor(r2s, off); r2d += __shfl_xor(r2d, off);
            r3s += __shfl_xor(r3s, off); r3d += __shfl_xor(r3d, off);
        }
        if (lane == 0) {
            s_src[n0]     = r0s; s_dst[n0]     = r0d;
            s_src[n0 + 1] = r1s; s_dst[n0 + 1] = r1d;
            s_src[n0 + 2] = r2s; s_dst[n0 + 2] = r2d;
            s_src[n0 + 3] = r3s; s_dst[n0 + 3] = r3d;
        }
    }
}

// Kernel 2: per-tile LDS counting-sort by bucket. NO global atomics; all
// global writes are sequential & coalesced (full lines). gofs[tile][b] =
// exclusive offset of bucket b within its tile.
__global__ __launch_bounds__(256) void k_tilesort(
    const int* __restrict__ ei, int* __restrict__ bdata,
    int* __restrict__ gofs)
{
    __shared__ int cnt[NB];
    __shared__ int ofs[NB];
    __shared__ int cur[NB];
    __shared__ unsigned srt[TS];       // 16 KB
    __shared__ int wsum[4];

    const int tile = blockIdx.x;
    const int tid = threadIdx.x;
    const int base = tile * TS;
    const int tcnt = (NE - base < TS) ? (NE - base) : TS;

    for (int i = tid; i < NB; i += 256) cnt[i] = 0;
    __syncthreads();

    unsigned pk[16];
    #pragma unroll
    for (int j = 0; j < 16; ++j) {
        const int i = j * 256 + tid;
        if (i < tcnt) {
            const int e = base + i;
            const unsigned s = (unsigned)__builtin_nontemporal_load(ei + e);
            const unsigned d = (unsigned)__builtin_nontemporal_load(ei + NE + e);
            pk[j] = (s << 16) | d;
            atomicAdd(&cnt[d / DPB], 1);
        } else pk[j] = 0xFFFFFFFFu;
    }
    __syncthreads();

    // exclusive scan of cnt[0..1024): 4 values/thread, wave scans + combine
    {
        const int lane = tid & 63, wv = tid >> 6;
        const int i0 = tid * 4;
        const int v0 = cnt[i0], v1 = cnt[i0 + 1], v2 = cnt[i0 + 2], v3 = cnt[i0 + 3];
        const int s = v0 + v1 + v2 + v3;
        int inc = s;
        #pragma unroll
        for (int off = 1; off < 64; off <<= 1) {
            const int t = __shfl_up(inc, off);
            if (lane >= off) inc += t;
        }
        if (lane == 63) wsum[wv] = inc;
        __syncthreads();
        int wb = 0;
        #pragma unroll
        for (int w = 0; w < 3; ++w) if (w < wv) wb += wsum[w];
        int excl = wb + inc - s;
        ofs[i0] = excl;
        ofs[i0 + 1] = excl + v0;
        ofs[i0 + 2] = excl + v0 + v1;
        ofs[i0 + 3] = excl + v0 + v1 + v2;
        cur[i0] = ofs[i0]; cur[i0 + 1] = ofs[i0 + 1];
        cur[i0 + 2] = ofs[i0 + 2]; cur[i0 + 3] = ofs[i0 + 3];
    }
    __syncthreads();

    // LDS scatter into bucket order
    #pragma unroll
    for (int j = 0; j < 16; ++j) {
        if (pk[j] != 0xFFFFFFFFu) {
            const int b = (int)(pk[j] & 0xffffu) / DPB;
            const int pos = atomicAdd(&cur[b], 1);
            srt[pos] = pk[j];
        }
    }
    __syncthreads();

    // sequential write-out
    for (int i = tid; i < tcnt; i += 256)
        ((unsigned*)bdata)[base + i] = srt[i];
    for (int i = tid; i < NB; i += 256)
        gofs[tile * NB + i] = ofs[i];
}

// Kernel 3: per-bucket gather. Stage the bucket's 245 tile-segments into
// LDS, counting-sort by dst (49 dsts), then wave=dst/lane=feature gather
// with recomputed ev = exp(lrelu(s_src+s_dst)), normalize, ELU. No atomics.
__global__ __launch_bounds__(256) void k_sortgather(
    const int* __restrict__ gofs, const int* __restrict__ bdata,
    const float* __restrict__ s_src, const float* __restrict__ s_dst,
    const __hip_bfloat16* __restrict__ Whb, float* __restrict__ out)
{
    __shared__ unsigned raw[2048];
    __shared__ unsigned srt[2048];
    __shared__ int cnt[64];
    __shared__ int ofs2[65];
    __shared__ int cur[64];
    __shared__ int wsum[4];

    const int b = blockIdx.x;
    const int tid = threadIdx.x;
    const int lane = tid & 63;
    const int wv = tid >> 6;
    const int d0 = b * DPB;
    const int nd = (NN - d0 < DPB) ? (NN - d0) : DPB;

    if (tid < 64) cnt[tid] = 0;

    // segment length for this thread's tile
    int c = 0, o = 0;
    if (tid < NT) {
        o = gofs[tid * NB + b];
        const int tc = (tid < NT - 1) ? TS : (NE - (NT - 1) * TS);
        const int nxt = (b < NB - 1) ? gofs[tid * NB + b + 1] : tc;
        c = nxt - o;
    }
    // exclusive scan over 256 segment lengths
    int inc = c;
    #pragma unroll
    for (int off = 1; off < 64; off <<= 1) {
        const int t = __shfl_up(inc, off);
        if (lane >= off) inc += t;
    }
    if (lane == 63) wsum[wv] = inc;
    __syncthreads();
    int wb = 0;
    #pragma unroll
    for (int w = 0; w < 3; ++w) if (w < wv) wb += wsum[w];
    const int segbase = wb + inc - c;
    const int tot = wsum[0] + wsum[1] + wsum[2] + wsum[3];

    // copy this thread's segment into LDS
    for (int k = 0; k < c; ++k)
        raw[segbase + k] = ((const unsigned*)bdata)[tid * TS + o + k];
    __syncthreads();

    // count by dst
    for (int i = tid; i < tot; i += 256)
        atomicAdd(&cnt[(int)(raw[i] & 0xffffu) - d0], 1);
    __syncthreads();

    // exclusive scan over 49 counts (wave 0)
    if (tid < 64) {
        const int cc = (tid < nd) ? cnt[tid] : 0;
        int in2 = cc;
        #pragma unroll
        for (int off = 1; off < 64; off <<= 1) {
            const int t = __shfl_up(in2, off);
            if (tid >= off) in2 += t;
        }
        ofs2[tid + 1] = in2;
        if (tid == 0) ofs2[0] = 0;
        cur[tid] = in2 - cc;
    }
    __syncthreads();

    // LDS scatter into dst order
    for (int i = tid; i < tot; i += 256) {
        const unsigned p = raw[i];
        const int j = (int)(p & 0xffffu) - d0;
        const int pos = atomicAdd(&cur[j], 1);
        srt[pos] = p;
    }
    __syncthreads();

    // gather: wave = dst, lane = feature
    for (int j = wv; j < nd; j += 4) {
        const int d = d0 + j;
        const float sd = s_dst[d];
        const int beg = ofs2[j];
        const int end = ofs2[j + 1];
        float acc = 0.f, den = 0.f;
        int i = beg;
        for (; i + 4 <= end; i += 4) {
            const unsigned p0 = srt[i];
            const unsigned p1 = srt[i + 1];
            const unsigned p2 = srt[i + 2];
            const unsigned p3 = srt[i + 3];
            const int s0 = p0 >> 16, s1 = p1 >> 16, s2 = p2 >> 16, s3 = p3 >> 16;
            float v0 = s_src[s0] + sd; v0 = (v0 > 0.f) ? v0 : NEG * v0;
            float v1 = s_src[s1] + sd; v1 = (v1 > 0.f) ? v1 : NEG * v1;
            float v2 = s_src[s2] + sd; v2 = (v2 > 0.f) ? v2 : NEG * v2;
            float v3 = s_src[s3] + sd; v3 = (v3 > 0.f) ? v3 : NEG * v3;
            const float e0 = __expf(v0);
            const float e1 = __expf(v1);
            const float e2 = __expf(v2);
            const float e3 = __expf(v3);
            acc = fmaf(e0, __bfloat162float(Whb[(size_t)s0 * FOUT + lane]), acc);
            acc = fmaf(e1, __bfloat162float(Whb[(size_t)s1 * FOUT + lane]), acc);
            acc = fmaf(e2, __bfloat162float(Whb[(size_t)s2 * FOUT + lane]), acc);
            acc = fmaf(e3, __bfloat162float(Whb[(size_t)s3 * FOUT + lane]), acc);
            den += (e0 + e1) + (e2 + e3);
        }
        for (; i < end; ++i) {
            const unsigned p0 = srt[i];
            const int s0 = p0 >> 16;
            float v0 = s_src[s0] + sd; v0 = (v0 > 0.f) ? v0 : NEG * v0;
            const float e0 = __expf(v0);
            acc = fmaf(e0, __bfloat162float(Whb[(size_t)s0 * FOUT + lane]), acc);
            den += e0;
        }
        const float r = acc / (den + 1e-16f);
        out[(size_t)d * FOUT + lane] = (r > 0.f) ? r : expm1f(r);
    }
}

extern "C" void kernel_launch(void* const* d_in, const int* in_sizes, int n_in,
                              void* d_out, int out_size, void* d_ws, size_t ws_size,
                              hipStream_t stream)
{
    const float* x     = (const float*)d_in[0];
    const int*   ei    = (const int*)d_in[1];   // [2,E]: src = ei[0..E), dst = ei[E..2E)
    const float* W     = (const float*)d_in[2];
    const float* a_src = (const float*)d_in[3];
    const float* a_dst = (const float*)d_in[4];
    float* out = (float*)d_out;

    // Workspace: Whb 6.4 MB | s_src 200 KB | s_dst 200 KB | gofs 1 MB |
    // bdata 4 MB  -> ~11.8 MB. No memsets needed (everything fully written).
    float* ws    = (float*)d_ws;
    __hip_bfloat16* Whb = (__hip_bfloat16*)ws;
    float* s_src = ws + (size_t)NN * FOUT / 2;
    float* s_dst = s_src + NN;
    int*   gofs  = (int*)(s_dst + NN);
    int*   bdata = gofs + (size_t)NT * NB;

    k_gemm<<<1024, 256, 0, stream>>>(x, W, a_src, a_dst, Whb, s_src, s_dst);
    k_tilesort<<<NT, 256, 0, stream>>>(ei, bdata, gofs);
    k_sortgather<<<NBUSED, 256, 0, stream>>>(gofs, bdata, s_src, s_dst, Whb, out);
}

// Round 6
// 138.780 us; speedup vs baseline: 1.9274x; 1.1620x over previous
//
#include <hip/hip_runtime.h>
#include <hip/hip_bf16.h>
#include <math.h>

#define NN 50000
#define NE 1000000
#define FIN 128
#define FOUT 64
#define NEG 0.2f

#define NB   2048     // dst-range buckets
#define DPB  25       // dsts per bucket; 2000*25 = 50000 exact
#define NBUSED 2000
#define TS   4096     // edges per sort tile
#define NT   245      // 244 full tiles + 576-edge tail (must be <= 256)

using short8  = __attribute__((ext_vector_type(8))) short;
using floatx4 = __attribute__((ext_vector_type(4))) float;

static __device__ __forceinline__ short f2bf(float f) {
    __hip_bfloat16 h = __float2bfloat16(f);
    return *(short*)&h;
}

// Kernel 1: MFMA gemm. One wave per 16-row strip of x. D = A(16x128)·B(128x64)
// as 4 K-steps x 4 N-tiles of mfma_f32_16x16x32_bf16. Layouts (m89/m120):
// A[m=lane&15][k=quad*8+j], B[k=quad*8+j][n=lane&15], C: col=lane&15,
// row=quad*4+reg. Fused s_src/s_dst via in-quad shfl reduce. No LDS.
__global__ __launch_bounds__(256) void k_gemm(
    const float* __restrict__ x, const float* __restrict__ W,
    const float* __restrict__ a_src, const float* __restrict__ a_dst,
    __hip_bfloat16* __restrict__ Whb, float* __restrict__ s_src,
    float* __restrict__ s_dst)
{
    const int lane = threadIdx.x & 63;
    const int wave = threadIdx.x >> 6;
    const int col  = lane & 15;
    const int quad = lane >> 4;

    const int strip = blockIdx.x * 4 + wave;
    if (strip >= NN / 16) return;          // 3125 strips, 50000 rows exact
    const int row0 = strip * 16;

    // B fragments: bfr[kk][nt][j] = W[kk*32 + quad*8 + j][nt*16 + col]
    short8 bfr[4][4];
    #pragma unroll
    for (int kk = 0; kk < 4; ++kk) {
        #pragma unroll
        for (int nt = 0; nt < 4; ++nt) {
            const float* wp = W + (kk * 32 + quad * 8) * FOUT + nt * 16 + col;
            #pragma unroll
            for (int j = 0; j < 8; ++j)
                bfr[kk][nt][j] = f2bf(wp[j * FOUT]);
        }
    }

    floatx4 acc[4] = {{0.f,0.f,0.f,0.f},{0.f,0.f,0.f,0.f},
                      {0.f,0.f,0.f,0.f},{0.f,0.f,0.f,0.f}};

    const float* xrow = x + (size_t)(row0 + col) * FIN + quad * 8;
    #pragma unroll
    for (int kk = 0; kk < 4; ++kk) {
        const float4 u0 = *(const float4*)(xrow + kk * 32);
        const float4 u1 = *(const float4*)(xrow + kk * 32 + 4);
        short8 af;
        af[0] = f2bf(u0.x); af[1] = f2bf(u0.y);
        af[2] = f2bf(u0.z); af[3] = f2bf(u0.w);
        af[4] = f2bf(u1.x); af[5] = f2bf(u1.y);
        af[6] = f2bf(u1.z); af[7] = f2bf(u1.w);
        #pragma unroll
        for (int nt = 0; nt < 4; ++nt)
            acc[nt] = __builtin_amdgcn_mfma_f32_16x16x32_bf16(
                af, bfr[kk][nt], acc[nt], 0, 0, 0);
    }

    const float av0 = a_src[col], av1 = a_src[16 + col];
    const float av2 = a_src[32 + col], av3 = a_src[48 + col];
    const float bv0 = a_dst[col], bv1 = a_dst[16 + col];
    const float bv2 = a_dst[32 + col], bv3 = a_dst[48 + col];

    float ps[4], pd[4];
    #pragma unroll
    for (int reg = 0; reg < 4; ++reg) {
        ps[reg] = acc[0][reg] * av0 + acc[1][reg] * av1
                + acc[2][reg] * av2 + acc[3][reg] * av3;
        pd[reg] = acc[0][reg] * bv0 + acc[1][reg] * bv1
                + acc[2][reg] * bv2 + acc[3][reg] * bv3;
    }

    #pragma unroll
    for (int nt = 0; nt < 4; ++nt)
        #pragma unroll
        for (int reg = 0; reg < 4; ++reg)
            Whb[(size_t)(row0 + quad * 4 + reg) * FOUT + nt * 16 + col] =
                __float2bfloat16(acc[nt][reg]);

    // reduce across the 16 lanes of each quad (row sums)
    #pragma unroll
    for (int off = 1; off < 16; off <<= 1) {
        #pragma unroll
        for (int reg = 0; reg < 4; ++reg) {
            ps[reg] += __shfl_xor(ps[reg], off);
            pd[reg] += __shfl_xor(pd[reg], off);
        }
    }
    if (col == 0) {
        #pragma unroll
        for (int reg = 0; reg < 4; ++reg) {
            s_src[row0 + quad * 4 + reg] = ps[reg];
            s_dst[row0 + quad * 4 + reg] = pd[reg];
        }
    }
}

// Kernel 2: per-tile LDS counting-sort by bucket (512 threads for latency
// hiding). No global atomics; sequential coalesced writes. gofs written
// directly from scan registers.
__global__ __launch_bounds__(512) void k_tilesort(
    const int* __restrict__ ei, unsigned* __restrict__ bdata,
    int* __restrict__ gofs)
{
    __shared__ int cnt[NB];            // 8 KB
    __shared__ int cur[NB];            // 8 KB
    __shared__ unsigned srt[TS];       // 16 KB
    __shared__ int wsum[8];

    const int tile = blockIdx.x;
    const int tid = threadIdx.x;
    const int base = tile * TS;
    const int tcnt = (NE - base < TS) ? (NE - base) : TS;

    for (int i = tid; i < NB; i += 512) cnt[i] = 0;
    __syncthreads();

    unsigned pk[8];
    #pragma unroll
    for (int j = 0; j < 8; ++j) {
        const int i = j * 512 + tid;
        if (i < tcnt) {
            const int e = base + i;
            const unsigned s = (unsigned)__builtin_nontemporal_load(ei + e);
            const unsigned d = (unsigned)__builtin_nontemporal_load(ei + NE + e);
            pk[j] = (s << 16) | d;
            atomicAdd(&cnt[d / DPB], 1);
        } else pk[j] = 0xFFFFFFFFu;    // > any real packed value (s < 50000)
    }
    __syncthreads();

    // exclusive scan of cnt[0..2048): 4 values/thread, 8 wave scans + combine
    {
        const int lane = tid & 63, wv = tid >> 6;
        const int i0 = tid * 4;
        const int v0 = cnt[i0], v1 = cnt[i0 + 1];
        const int v2 = cnt[i0 + 2], v3 = cnt[i0 + 3];
        const int s = v0 + v1 + v2 + v3;
        int inc = s;
        #pragma unroll
        for (int off = 1; off < 64; off <<= 1) {
            const int t = __shfl_up(inc, off);
            if (lane >= off) inc += t;
        }
        if (lane == 63) wsum[wv] = inc;
        __syncthreads();
        int wb = 0;
        #pragma unroll
        for (int w = 0; w < 7; ++w) if (w < wv) wb += wsum[w];
        const int excl = wb + inc - s;
        cur[i0]     = excl;
        cur[i0 + 1] = excl + v0;
        cur[i0 + 2] = excl + v0 + v1;
        cur[i0 + 3] = excl + v0 + v1 + v2;
        int4 g = make_int4(excl, excl + v0, excl + v0 + v1, excl + v0 + v1 + v2);
        *(int4*)(gofs + (size_t)tile * NB + i0) = g;
    }
    __syncthreads();

    // LDS scatter into bucket order
    #pragma unroll
    for (int j = 0; j < 8; ++j) {
        if (pk[j] != 0xFFFFFFFFu) {
            const int b = (int)(pk[j] & 0xffffu) / DPB;
            const int pos = atomicAdd(&cur[b], 1);
            srt[pos] = pk[j];
        }
    }
    __syncthreads();

    for (int i = tid; i < tcnt; i += 512)
        bdata[base + i] = srt[i];
}

// Kernel 3: per-bucket gather (25 dsts, ~500 edges). Stage 245 tile-segments
// into LDS, counting-sort by dst, wave=dst/lane=feature gather with
// recomputed ev = exp(lrelu(s_src+s_dst)), normalize, ELU. ~8.7 KB LDS ->
// 8 blocks/CU; grid 2000.
__global__ __launch_bounds__(256) void k_sortgather(
    const int* __restrict__ gofs, const unsigned* __restrict__ bdata,
    const float* __restrict__ s_src, const float* __restrict__ s_dst,
    const __hip_bfloat16* __restrict__ Whb, float* __restrict__ out)
{
    __shared__ unsigned raw[1024];     // mean fill ~500, max ~610
    __shared__ unsigned srt[1024];
    __shared__ int cnt[32];
    __shared__ int ofs2[33];
    __shared__ int cur[32];
    __shared__ int wsum[4];

    const int b = blockIdx.x;
    const int tid = threadIdx.x;
    const int lane = tid & 63;
    const int wv = tid >> 6;
    const int d0 = b * DPB;

    if (tid < 32) cnt[tid] = 0;

    // this thread's tile-segment
    int c = 0, o = 0;
    if (tid < NT) {
        o = gofs[tid * NB + b];
        const int tc = (tid < NT - 1) ? TS : (NE - (NT - 1) * TS);
        const int nxt = (b < NB - 1) ? gofs[tid * NB + b + 1] : tc;
        c = nxt - o;
    }
    int inc = c;
    #pragma unroll
    for (int off = 1; off < 64; off <<= 1) {
        const int t = __shfl_up(inc, off);
        if (lane >= off) inc += t;
    }
    if (lane == 63) wsum[wv] = inc;
    __syncthreads();
    int wb = 0;
    #pragma unroll
    for (int w = 0; w < 3; ++w) if (w < wv) wb += wsum[w];
    const int segbase = wb + inc - c;
    const int tot = wsum[0] + wsum[1] + wsum[2] + wsum[3];

    for (int k = 0; k < c; ++k)
        raw[segbase + k] = bdata[(size_t)tid * TS + o + k];
    __syncthreads();

    for (int i = tid; i < tot; i += 256)
        atomicAdd(&cnt[(int)(raw[i] & 0xffffu) - d0], 1);
    __syncthreads();

    if (tid < 32) {
        const int cc = (tid < DPB) ? cnt[tid] : 0;
        int in2 = cc;
        #pragma unroll
        for (int off = 1; off < 32; off <<= 1) {
            const int t = __shfl_up(in2, off);
            if (tid >= off) in2 += t;
        }
        ofs2[tid + 1] = in2;
        if (tid == 0) ofs2[0] = 0;
        cur[tid] = in2 - cc;
    }
    __syncthreads();

    for (int i = tid; i < tot; i += 256) {
        const unsigned p = raw[i];
        const int j = (int)(p & 0xffffu) - d0;
        const int pos = atomicAdd(&cur[j], 1);
        srt[pos] = p;
    }
    __syncthreads();

    // gather: wave = dst, lane = feature
    for (int j = wv; j < DPB; j += 4) {
        const int d = d0 + j;
        const float sd = s_dst[d];
        const int beg = ofs2[j];
        const int end = ofs2[j + 1];
        float acc = 0.f, den = 0.f;
        int i = beg;
        for (; i + 4 <= end; i += 4) {
            const unsigned p0 = srt[i];
            const unsigned p1 = srt[i + 1];
            const unsigned p2 = srt[i + 2];
            const unsigned p3 = srt[i + 3];
            const int s0 = p0 >> 16, s1 = p1 >> 16, s2 = p2 >> 16, s3 = p3 >> 16;
            float v0 = s_src[s0] + sd; v0 = (v0 > 0.f) ? v0 : NEG * v0;
            float v1 = s_src[s1] + sd; v1 = (v1 > 0.f) ? v1 : NEG * v1;
            float v2 = s_src[s2] + sd; v2 = (v2 > 0.f) ? v2 : NEG * v2;
            float v3 = s_src[s3] + sd; v3 = (v3 > 0.f) ? v3 : NEG * v3;
            const float e0 = __expf(v0);
            const float e1 = __expf(v1);
            const float e2 = __expf(v2);
            const float e3 = __expf(v3);
            acc = fmaf(e0, __bfloat162float(Whb[(size_t)s0 * FOUT + lane]), acc);
            acc = fmaf(e1, __bfloat162float(Whb[(size_t)s1 * FOUT + lane]), acc);
            acc = fmaf(e2, __bfloat162float(Whb[(size_t)s2 * FOUT + lane]), acc);
            acc = fmaf(e3, __bfloat162float(Whb[(size_t)s3 * FOUT + lane]), acc);
            den += (e0 + e1) + (e2 + e3);
        }
        for (; i < end; ++i) {
            const unsigned p0 = srt[i];
            const int s0 = p0 >> 16;
            float v0 = s_src[s0] + sd; v0 = (v0 > 0.f) ? v0 : NEG * v0;
            const float e0 = __expf(v0);
            acc = fmaf(e0, __bfloat162float(Whb[(size_t)s0 * FOUT + lane]), acc);
            den += e0;
        }
        const float r = acc / (den + 1e-16f);
        out[(size_t)d * FOUT + lane] = (r > 0.f) ? r : expm1f(r);
    }
}

extern "C" void kernel_launch(void* const* d_in, const int* in_sizes, int n_in,
                              void* d_out, int out_size, void* d_ws, size_t ws_size,
                              hipStream_t stream)
{
    const float* x     = (const float*)d_in[0];
    const int*   ei    = (const int*)d_in[1];   // [2,E]: src = ei[0..E), dst = ei[E..2E)
    const float* W     = (const float*)d_in[2];
    const float* a_src = (const float*)d_in[3];
    const float* a_dst = (const float*)d_in[4];
    float* out = (float*)d_out;

    // Workspace: Whb 6.4 MB | s_src 200 KB | s_dst 200 KB | gofs 2 MB |
    // bdata 4 MB  -> ~12.8 MB. No memsets needed.
    float* ws    = (float*)d_ws;
    __hip_bfloat16* Whb = (__hip_bfloat16*)ws;
    float* s_src = ws + (size_t)NN * FOUT / 2;
    float* s_dst = s_src + NN;
    int*   gofs  = (int*)(s_dst + NN);
    unsigned* bdata = (unsigned*)(gofs + (size_t)NT * NB);

    k_gemm<<<(NN / 16 + 3) / 4, 256, 0, stream>>>(x, W, a_src, a_dst,
                                                  Whb, s_src, s_dst);
    k_tilesort<<<NT, 512, 0, stream>>>(ei, bdata, gofs);
    k_sortgather<<<NBUSED, 256, 0, stream>>>(gofs, bdata, s_src, s_dst, Whb, out);
}

// Round 7
// 135.692 us; speedup vs baseline: 1.9713x; 1.0228x over previous
//
#include <hip/hip_runtime.h>
#include <hip/hip_bf16.h>
#include <math.h>

#define NN 50000
#define NE 1000000
#define FIN 128
#define FOUT 64
#define NEG 0.2f

#define NB   2048     // dst-range buckets
#define DPB  25       // dsts per bucket; 2000*25 = 50000 exact
#define NBUSED 2000
#define TS   4096     // edges per sort tile
#define NT   245      // 244 full tiles + 576-edge tail (<= 256)
#define NTP  256      // padded row stride of transposed gofs
#define GEMM_BLKS 782 // ceil(3125 strips / 4 waves)

using short8  = __attribute__((ext_vector_type(8))) short;
using floatx4 = __attribute__((ext_vector_type(4))) float;

static __device__ __forceinline__ short f2bf(float f) {
    __hip_bfloat16 h = __float2bfloat16(f);
    return *(short*)&h;
}

// Fused front kernel: blocks [0,GEMM_BLKS) do the MFMA gemm; blocks
// [GEMM_BLKS, GEMM_BLKS+NT) do the per-tile LDS counting-sort. The two
// roles touch disjoint inputs/outputs and run CONCURRENTLY (they were
// serialized as separate kernels before: cost max() instead of sum).
__global__ __launch_bounds__(256) void k_front(
    const float* __restrict__ x, const float* __restrict__ W,
    const float* __restrict__ a_src, const float* __restrict__ a_dst,
    const int* __restrict__ ei,
    __hip_bfloat16* __restrict__ Whb, float* __restrict__ s_src,
    float* __restrict__ s_dst,
    unsigned* __restrict__ bdata, int* __restrict__ gofs)
{
    // tilesort role LDS (gemm role ignores; 32 KB caps LDS-occupancy at 5/CU)
    __shared__ int cnt[NB];            // 8 KB
    __shared__ int cur[NB];            // 8 KB
    __shared__ unsigned srt[TS];       // 16 KB
    __shared__ int wsum[4];

    const int tid  = threadIdx.x;
    const int lane = tid & 63;
    const int wv   = tid >> 6;

    if (blockIdx.x < GEMM_BLKS) {
        // ---------------- GEMM role ----------------
        // One wave per 16-row strip. D = A(16x128)·B(128x64) via 4 K-steps x
        // 4 N-tiles of mfma_f32_16x16x32_bf16. A[m=lane&15][k=quad*8+j],
        // B[k=quad*8+j][n=lane&15], C: col=lane&15, row=quad*4+reg.
        const int col  = lane & 15;
        const int quad = lane >> 4;
        const int strip = blockIdx.x * 4 + wv;
        if (strip >= NN / 16) return;          // 3125 strips
        const int row0 = strip * 16;

        short8 bfr[4][4];
        #pragma unroll
        for (int kk = 0; kk < 4; ++kk) {
            #pragma unroll
            for (int nt = 0; nt < 4; ++nt) {
                const float* wp = W + (kk * 32 + quad * 8) * FOUT + nt * 16 + col;
                #pragma unroll
                for (int j = 0; j < 8; ++j)
                    bfr[kk][nt][j] = f2bf(wp[j * FOUT]);
            }
        }

        floatx4 acc[4] = {{0.f,0.f,0.f,0.f},{0.f,0.f,0.f,0.f},
                          {0.f,0.f,0.f,0.f},{0.f,0.f,0.f,0.f}};

        const float* xrow = x + (size_t)(row0 + col) * FIN + quad * 8;
        #pragma unroll
        for (int kk = 0; kk < 4; ++kk) {
            const float4 u0 = *(const float4*)(xrow + kk * 32);
            const float4 u1 = *(const float4*)(xrow + kk * 32 + 4);
            short8 af;
            af[0] = f2bf(u0.x); af[1] = f2bf(u0.y);
            af[2] = f2bf(u0.z); af[3] = f2bf(u0.w);
            af[4] = f2bf(u1.x); af[5] = f2bf(u1.y);
            af[6] = f2bf(u1.z); af[7] = f2bf(u1.w);
            #pragma unroll
            for (int nt = 0; nt < 4; ++nt)
                acc[nt] = __builtin_amdgcn_mfma_f32_16x16x32_bf16(
                    af, bfr[kk][nt], acc[nt], 0, 0, 0);
        }

        const float av0 = a_src[col], av1 = a_src[16 + col];
        const float av2 = a_src[32 + col], av3 = a_src[48 + col];
        const float bv0 = a_dst[col], bv1 = a_dst[16 + col];
        const float bv2 = a_dst[32 + col], bv3 = a_dst[48 + col];

        float ps[4], pd[4];
        #pragma unroll
        for (int reg = 0; reg < 4; ++reg) {
            ps[reg] = acc[0][reg] * av0 + acc[1][reg] * av1
                    + acc[2][reg] * av2 + acc[3][reg] * av3;
            pd[reg] = acc[0][reg] * bv0 + acc[1][reg] * bv1
                    + acc[2][reg] * bv2 + acc[3][reg] * bv3;
        }

        #pragma unroll
        for (int nt = 0; nt < 4; ++nt)
            #pragma unroll
            for (int reg = 0; reg < 4; ++reg)
                Whb[(size_t)(row0 + quad * 4 + reg) * FOUT + nt * 16 + col] =
                    __float2bfloat16(acc[nt][reg]);

        #pragma unroll
        for (int off = 1; off < 16; off <<= 1) {
            #pragma unroll
            for (int reg = 0; reg < 4; ++reg) {
                ps[reg] += __shfl_xor(ps[reg], off);
                pd[reg] += __shfl_xor(pd[reg], off);
            }
        }
        if (col == 0) {
            #pragma unroll
            for (int reg = 0; reg < 4; ++reg) {
                s_src[row0 + quad * 4 + reg] = ps[reg];
                s_dst[row0 + quad * 4 + reg] = pd[reg];
            }
        }
        return;
    }

    // ---------------- TILESORT role ----------------
    const int tile = blockIdx.x - GEMM_BLKS;
    const int base = tile * TS;
    const int tcnt = (NE - base < TS) ? (NE - base) : TS;

    for (int i = tid; i < NB; i += 256) cnt[i] = 0;
    __syncthreads();

    unsigned pk[16];
    #pragma unroll
    for (int j = 0; j < 16; ++j) {
        const int i = j * 256 + tid;
        if (i < tcnt) {
            const int e = base + i;
            const unsigned s = (unsigned)__builtin_nontemporal_load(ei + e);
            const unsigned d = (unsigned)__builtin_nontemporal_load(ei + NE + e);
            pk[j] = (s << 16) | d;
            atomicAdd(&cnt[d / DPB], 1);
        } else pk[j] = 0xFFFFFFFFu;
    }
    __syncthreads();

    // exclusive scan of cnt[0..2048): 8 values/thread, wave scans + combine
    {
        const int i0 = tid * 8;
        int v[8], s = 0;
        #pragma unroll
        for (int j = 0; j < 8; ++j) { v[j] = cnt[i0 + j]; s += v[j]; }
        int inc = s;
        #pragma unroll
        for (int off = 1; off < 64; off <<= 1) {
            const int t = __shfl_up(inc, off);
            if (lane >= off) inc += t;
        }
        if (lane == 63) wsum[wv] = inc;
        __syncthreads();
        int wb = 0;
        #pragma unroll
        for (int w = 0; w < 3; ++w) if (w < wv) wb += wsum[w];
        int excl = wb + inc - s;
        int g[8];
        #pragma unroll
        for (int j = 0; j < 8; ++j) { cur[i0 + j] = excl; g[j] = excl; excl += v[j]; }
        *(int4*)(gofs + (size_t)tile * NB + i0)     = make_int4(g[0], g[1], g[2], g[3]);
        *(int4*)(gofs + (size_t)tile * NB + i0 + 4) = make_int4(g[4], g[5], g[6], g[7]);
    }
    __syncthreads();

    #pragma unroll
    for (int j = 0; j < 16; ++j) {
        if (pk[j] != 0xFFFFFFFFu) {
            const int b = (int)(pk[j] & 0xffffu) / DPB;
            const int pos = atomicAdd(&cur[b], 1);
            srt[pos] = pk[j];
        }
    }
    __syncthreads();

    for (int i = tid; i < tcnt; i += 256)
        bdata[base + i] = srt[i];
}

// Transpose gofs[t][b] -> gofs_t[b][t] (row stride NTP=256, padded).
// Turns sortgather's 245 strided 4B reads into 2 coalesced row reads.
__global__ __launch_bounds__(256) void k_transp(
    const int* __restrict__ gofs, int* __restrict__ gofs_t)
{
    __shared__ int tb[32][33];
    const int bi = blockIdx.x & 63;    // 2048/32 bucket tiles
    const int ti = blockIdx.x >> 6;    // 8 t-tiles cover 256 >= NT
    const int r = threadIdx.x >> 5;    // 0..7
    const int c = threadIdx.x & 31;
    for (int rr = r; rr < 32; rr += 8) {
        const int t = ti * 32 + rr;
        tb[rr][c] = (t < NT) ? gofs[(size_t)t * NB + bi * 32 + c] : 0;
    }
    __syncthreads();
    for (int rr = r; rr < 32; rr += 8) {
        const int b = bi * 32 + rr;
        gofs_t[(size_t)b * NTP + ti * 32 + c] = tb[c][rr];
    }
}

// Per-bucket gather (25 dsts, ~500 edges). Coalesced gofs_t reads, LDS
// counting-sort by dst, streamed ev-precompute into LDS (detaches random
// s_src loads + exp from the gather chain), then wave=dst/lane=feature
// gather unrolled x8 (8 Whb rows in flight). Normalize + ELU fused.
__global__ __launch_bounds__(256) void k_sortgather(
    const int* __restrict__ gofs_t, const unsigned* __restrict__ bdata,
    const float* __restrict__ s_src, const float* __restrict__ s_dst,
    const __hip_bfloat16* __restrict__ Whb, float* __restrict__ out)
{
    __shared__ unsigned raw[1024];     // mean fill ~500 (23 sigma headroom)
    __shared__ unsigned srt[1024];
    __shared__ float evs[1024];
    __shared__ int cnt[32];
    __shared__ int ofs2[33];
    __shared__ int cur[32];
    __shared__ int wsum[4];

    const int b = blockIdx.x;
    const int tid = threadIdx.x;
    const int lane = tid & 63;
    const int wv = tid >> 6;
    const int d0 = b * DPB;

    if (tid < 32) cnt[tid] = 0;

    // this thread's tile-segment: offset within tile + length, both from
    // coalesced transposed-gofs rows b and b+1 (b+1 <= 2000 < 2048; bucket
    // ids are < 2000, so row 2000 holds each tile's total -> no edge case)
    int c = 0, o = 0;
    if (tid < NT) {
        o = gofs_t[(size_t)b * NTP + tid];
        c = gofs_t[(size_t)(b + 1) * NTP + tid] - o;
    }
    int inc = c;
    #pragma unroll
    for (int off = 1; off < 64; off <<= 1) {
        const int t = __shfl_up(inc, off);
        if (lane >= off) inc += t;
    }
    if (lane == 63) wsum[wv] = inc;
    __syncthreads();
    int wb = 0;
    #pragma unroll
    for (int w = 0; w < 3; ++w) if (w < wv) wb += wsum[w];
    const int segbase = wb + inc - c;
    const int tot = wsum[0] + wsum[1] + wsum[2] + wsum[3];

    for (int k = 0; k < c; ++k)
        raw[segbase + k] = bdata[(size_t)tid * TS + o + k];
    __syncthreads();

    for (int i = tid; i < tot; i += 256)
        atomicAdd(&cnt[(int)(raw[i] & 0xffffu) - d0], 1);
    __syncthreads();

    if (tid < 32) {
        const int cc = (tid < DPB) ? cnt[tid] : 0;
        int in2 = cc;
        #pragma unroll
        for (int off = 1; off < 32; off <<= 1) {
            const int t = __shfl_up(in2, off);
            if (tid >= off) in2 += t;
        }
        ofs2[tid + 1] = in2;
        if (tid == 0) ofs2[0] = 0;
        cur[tid] = in2 - cc;
    }
    __syncthreads();

    for (int i = tid; i < tot; i += 256) {
        const unsigned p = raw[i];
        const int j = (int)(p & 0xffffu) - d0;
        const int pos = atomicAdd(&cur[j], 1);
        srt[pos] = p;
    }
    __syncthreads();

    // streamed ev precompute (independent loads, high MLP)
    for (int i = tid; i < tot; i += 256) {
        const unsigned p = srt[i];
        float v = s_src[p >> 16] + s_dst[p & 0xffffu];
        v = (v > 0.f) ? v : NEG * v;
        evs[i] = __expf(v);
    }
    __syncthreads();

    // gather: wave = dst, lane = feature; unroll 8
    for (int j = wv; j < DPB; j += 4) {
        const int d = d0 + j;
        const int beg = ofs2[j];
        const int end = ofs2[j + 1];
        float acc = 0.f, den = 0.f;
        int i = beg;
        for (; i + 8 <= end; i += 8) {
            int ss[8]; float ee[8], w[8];
            #pragma unroll
            for (int k = 0; k < 8; ++k) {
                ss[k] = (int)(srt[i + k] >> 16);
                ee[k] = evs[i + k];
            }
            #pragma unroll
            for (int k = 0; k < 8; ++k)
                w[k] = __bfloat162float(Whb[(size_t)ss[k] * FOUT + lane]);
            #pragma unroll
            for (int k = 0; k < 8; ++k) {
                acc = fmaf(ee[k], w[k], acc);
                den += ee[k];
            }
        }
        for (; i < end; ++i) {
            const int s0 = (int)(srt[i] >> 16);
            const float e0 = evs[i];
            acc = fmaf(e0, __bfloat162float(Whb[(size_t)s0 * FOUT + lane]), acc);
            den += e0;
        }
        const float r = acc / (den + 1e-16f);
        out[(size_t)d * FOUT + lane] = (r > 0.f) ? r : expm1f(r);
    }
}

extern "C" void kernel_launch(void* const* d_in, const int* in_sizes, int n_in,
                              void* d_out, int out_size, void* d_ws, size_t ws_size,
                              hipStream_t stream)
{
    const float* x     = (const float*)d_in[0];
    const int*   ei    = (const int*)d_in[1];   // [2,E]: src = ei[0..E), dst = ei[E..2E)
    const float* W     = (const float*)d_in[2];
    const float* a_src = (const float*)d_in[3];
    const float* a_dst = (const float*)d_in[4];
    float* out = (float*)d_out;

    // Workspace: Whb 6.4 MB | s_src 200 KB | s_dst 200 KB | gofs 2 MB |
    // gofs_t 2 MB | bdata 4 MB  -> ~14.8 MB. No memsets needed.
    float* ws    = (float*)d_ws;
    __hip_bfloat16* Whb = (__hip_bfloat16*)ws;
    float* s_src = ws + (size_t)NN * FOUT / 2;
    float* s_dst = s_src + NN;
    int*   gofs  = (int*)(s_dst + NN);
    int*   gofs_t = gofs + (size_t)NT * NB;
    unsigned* bdata = (unsigned*)(gofs_t + (size_t)NB * NTP);

    k_front<<<GEMM_BLKS + NT, 256, 0, stream>>>(x, W, a_src, a_dst, ei,
                                                Whb, s_src, s_dst, bdata, gofs);
    k_transp<<<512, 256, 0, stream>>>(gofs, gofs_t);
    k_sortgather<<<NBUSED, 256, 0, stream>>>(gofs_t, bdata, s_src, s_dst,
                                             Whb, out);
}

// Round 8
// 123.753 us; speedup vs baseline: 2.1615x; 1.0965x over previous
//
#include <hip/hip_runtime.h>
#include <hip/hip_bf16.h>
#include <math.h>

#define NN 50000
#define NE 1000000
#define FIN 128
#define FOUT 64
#define NEG 0.2f

#define NB   2048     // dst-range buckets
#define DPB  25       // dsts per bucket; 2000*25 = 50000 exact
#define NBUSED 2000
#define TS   4096     // edges per sort tile
#define NT   245      // 244 full tiles + 576-edge tail (<= 256)
#define NTP  256      // padded row stride of transposed gofs
#define TILE_BLKS 245
#define GEMM_BLKS 391 // ceil(3125 strips / 8 waves)

using short8  = __attribute__((ext_vector_type(8))) short;
using floatx4 = __attribute__((ext_vector_type(4))) float;

static __device__ __forceinline__ short f2bf(float f) {
    __hip_bfloat16 h = __float2bfloat16(f);
    return *(short*)&h;
}

// Fused front kernel, 512 threads. Blocks [0,TILE_BLKS) = per-tile LDS
// counting-sort (8 waves/block for LDS-atomic latency hiding — round-7's
// 4-wave/CU occupancy was the long pole). Blocks [TILE_BLKS, +GEMM_BLKS) =
// MFMA gemm (one wave per 16-row strip). Roles touch disjoint data and run
// concurrently; tilesort goes first in the grid (it's the long pole).
__global__ __launch_bounds__(512) void k_front(
    const float* __restrict__ x, const float* __restrict__ W,
    const float* __restrict__ a_src, const float* __restrict__ a_dst,
    const int* __restrict__ ei,
    __hip_bfloat16* __restrict__ Whb, float* __restrict__ s_src,
    float* __restrict__ s_dst,
    unsigned* __restrict__ bdata, int* __restrict__ gofs)
{
    __shared__ int cnt[NB];            // 8 KB
    __shared__ int cur[NB];            // 8 KB
    __shared__ unsigned srt[TS];       // 16 KB
    __shared__ int wsum[8];

    const int tid  = threadIdx.x;
    const int lane = tid & 63;
    const int wv   = tid >> 6;

    if (blockIdx.x >= TILE_BLKS) {
        // ---------------- GEMM role ----------------
        // D = A(16x128)·B(128x64) via 4 K-steps x 4 N-tiles of
        // mfma_f32_16x16x32_bf16. A[m=lane&15][k=quad*8+j],
        // B[k=quad*8+j][n=lane&15], C: col=lane&15, row=quad*4+reg.
        const int col  = lane & 15;
        const int quad = lane >> 4;
        const int strip = (blockIdx.x - TILE_BLKS) * 8 + wv;
        if (strip >= NN / 16) return;          // 3125 strips
        const int row0 = strip * 16;

        short8 bfr[4][4];
        #pragma unroll
        for (int kk = 0; kk < 4; ++kk) {
            #pragma unroll
            for (int nt = 0; nt < 4; ++nt) {
                const float* wp = W + (kk * 32 + quad * 8) * FOUT + nt * 16 + col;
                #pragma unroll
                for (int j = 0; j < 8; ++j)
                    bfr[kk][nt][j] = f2bf(wp[j * FOUT]);
            }
        }

        floatx4 acc[4] = {{0.f,0.f,0.f,0.f},{0.f,0.f,0.f,0.f},
                          {0.f,0.f,0.f,0.f},{0.f,0.f,0.f,0.f}};

        const float* xrow = x + (size_t)(row0 + col) * FIN + quad * 8;
        #pragma unroll
        for (int kk = 0; kk < 4; ++kk) {
            const float4 u0 = *(const float4*)(xrow + kk * 32);
            const float4 u1 = *(const float4*)(xrow + kk * 32 + 4);
            short8 af;
            af[0] = f2bf(u0.x); af[1] = f2bf(u0.y);
            af[2] = f2bf(u0.z); af[3] = f2bf(u0.w);
            af[4] = f2bf(u1.x); af[5] = f2bf(u1.y);
            af[6] = f2bf(u1.z); af[7] = f2bf(u1.w);
            #pragma unroll
            for (int nt = 0; nt < 4; ++nt)
                acc[nt] = __builtin_amdgcn_mfma_f32_16x16x32_bf16(
                    af, bfr[kk][nt], acc[nt], 0, 0, 0);
        }

        const float av0 = a_src[col], av1 = a_src[16 + col];
        const float av2 = a_src[32 + col], av3 = a_src[48 + col];
        const float bv0 = a_dst[col], bv1 = a_dst[16 + col];
        const float bv2 = a_dst[32 + col], bv3 = a_dst[48 + col];

        float ps[4], pd[4];
        #pragma unroll
        for (int reg = 0; reg < 4; ++reg) {
            ps[reg] = acc[0][reg] * av0 + acc[1][reg] * av1
                    + acc[2][reg] * av2 + acc[3][reg] * av3;
            pd[reg] = acc[0][reg] * bv0 + acc[1][reg] * bv1
                    + acc[2][reg] * bv2 + acc[3][reg] * bv3;
        }

        #pragma unroll
        for (int nt = 0; nt < 4; ++nt)
            #pragma unroll
            for (int reg = 0; reg < 4; ++reg)
                Whb[(size_t)(row0 + quad * 4 + reg) * FOUT + nt * 16 + col] =
                    __float2bfloat16(acc[nt][reg]);

        #pragma unroll
        for (int off = 1; off < 16; off <<= 1) {
            #pragma unroll
            for (int reg = 0; reg < 4; ++reg) {
                ps[reg] += __shfl_xor(ps[reg], off);
                pd[reg] += __shfl_xor(pd[reg], off);
            }
        }
        if (col == 0) {
            #pragma unroll
            for (int reg = 0; reg < 4; ++reg) {
                s_src[row0 + quad * 4 + reg] = ps[reg];
                s_dst[row0 + quad * 4 + reg] = pd[reg];
            }
        }
        return;
    }

    // ---------------- TILESORT role ----------------
    const int tile = blockIdx.x;
    const int base = tile * TS;
    const int tcnt = (NE - base < TS) ? (NE - base) : TS;

    for (int i = tid; i < NB; i += 512) cnt[i] = 0;
    __syncthreads();

    unsigned pk[8];
    #pragma unroll
    for (int j = 0; j < 8; ++j) {
        const int i = j * 512 + tid;
        if (i < tcnt) {
            const int e = base + i;
            const unsigned s = (unsigned)__builtin_nontemporal_load(ei + e);
            const unsigned d = (unsigned)__builtin_nontemporal_load(ei + NE + e);
            pk[j] = (s << 16) | d;
            atomicAdd(&cnt[d / DPB], 1);
        } else pk[j] = 0xFFFFFFFFu;
    }
    __syncthreads();

    // exclusive scan of cnt[0..2048): 4 values/thread, 8 wave scans + combine
    {
        const int i0 = tid * 4;
        const int v0 = cnt[i0], v1 = cnt[i0 + 1];
        const int v2 = cnt[i0 + 2], v3 = cnt[i0 + 3];
        const int s = v0 + v1 + v2 + v3;
        int inc = s;
        #pragma unroll
        for (int off = 1; off < 64; off <<= 1) {
            const int t = __shfl_up(inc, off);
            if (lane >= off) inc += t;
        }
        if (lane == 63) wsum[wv] = inc;
        __syncthreads();
        int wb = 0;
        #pragma unroll
        for (int w = 0; w < 7; ++w) if (w < wv) wb += wsum[w];
        const int excl = wb + inc - s;
        cur[i0]     = excl;
        cur[i0 + 1] = excl + v0;
        cur[i0 + 2] = excl + v0 + v1;
        cur[i0 + 3] = excl + v0 + v1 + v2;
        *(int4*)(gofs + (size_t)tile * NB + i0) =
            make_int4(excl, excl + v0, excl + v0 + v1, excl + v0 + v1 + v2);
    }
    __syncthreads();

    #pragma unroll
    for (int j = 0; j < 8; ++j) {
        if (pk[j] != 0xFFFFFFFFu) {
            const int b = (int)(pk[j] & 0xffffu) / DPB;
            const int pos = atomicAdd(&cur[b], 1);
            srt[pos] = pk[j];
        }
    }
    __syncthreads();

    for (int i = tid; i < tcnt; i += 512)
        bdata[base + i] = srt[i];
}

// Transpose gofs[t][b] -> gofs_t[b][t] (row stride NTP=256, padded).
__global__ __launch_bounds__(256) void k_transp(
    const int* __restrict__ gofs, int* __restrict__ gofs_t)
{
    __shared__ int tb[32][33];
    const int bi = blockIdx.x & 63;    // 2048/32 bucket tiles
    const int ti = blockIdx.x >> 6;    // 8 t-tiles cover 256 >= NT
    const int r = threadIdx.x >> 5;    // 0..7
    const int c = threadIdx.x & 31;
    for (int rr = r; rr < 32; rr += 8) {
        const int t = ti * 32 + rr;
        tb[rr][c] = (t < NT) ? gofs[(size_t)t * NB + bi * 32 + c] : 0;
    }
    __syncthreads();
    for (int rr = r; rr < 32; rr += 8) {
        const int b = bi * 32 + rr;
        gofs_t[(size_t)b * NTP + ti * 32 + c] = tb[c][rr];
    }
}

// Per-bucket gather (25 dsts, ~500 edges). XCD-aware bucket swizzle:
// consecutive buckets share bdata cache lines (tile-sorted layout), so map
// them to the SAME XCD (round-robin dispatch: blockIdx%8 = XCD) to stop
// cross-XCD line replication (58 MB fetch for 12.8 useful in r7).
// ev computed inside the LDS scatter pass (s_dst pre-staged in LDS).
__global__ __launch_bounds__(256) void k_sortgather(
    const int* __restrict__ gofs_t, const unsigned* __restrict__ bdata,
    const float* __restrict__ s_src, const float* __restrict__ s_dst,
    const __hip_bfloat16* __restrict__ Whb, float* __restrict__ out)
{
    __shared__ unsigned raw[1024];     // mean fill ~500 (23 sigma headroom)
    __shared__ unsigned srt[1024];
    __shared__ float evs[1024];
    __shared__ float sdl[32];
    __shared__ int cnt[32];
    __shared__ int ofs2[33];
    __shared__ int cur[32];
    __shared__ int wsum[4];

    const int b = (blockIdx.x & 7) * (NBUSED / 8) + (blockIdx.x >> 3);
    const int tid = threadIdx.x;
    const int lane = tid & 63;
    const int wv = tid >> 6;
    const int d0 = b * DPB;

    if (tid < 32) {
        cnt[tid] = 0;
        sdl[tid] = (tid < DPB) ? s_dst[d0 + tid] : 0.f;
    }

    // this thread's tile-segment from coalesced transposed-gofs rows
    int c = 0, o = 0;
    if (tid < NT) {
        o = gofs_t[(size_t)b * NTP + tid];
        c = gofs_t[(size_t)(b + 1) * NTP + tid] - o;
    }
    int inc = c;
    #pragma unroll
    for (int off = 1; off < 64; off <<= 1) {
        const int t = __shfl_up(inc, off);
        if (lane >= off) inc += t;
    }
    if (lane == 63) wsum[wv] = inc;
    __syncthreads();
    int wb = 0;
    #pragma unroll
    for (int w = 0; w < 3; ++w) if (w < wv) wb += wsum[w];
    const int segbase = wb + inc - c;
    const int tot = wsum[0] + wsum[1] + wsum[2] + wsum[3];

    for (int k = 0; k < c; ++k)
        raw[segbase + k] = bdata[(size_t)tid * TS + o + k];
    __syncthreads();

    for (int i = tid; i < tot; i += 256)
        atomicAdd(&cnt[(int)(raw[i] & 0xffffu) - d0], 1);
    __syncthreads();

    if (tid < 32) {
        const int cc = (tid < DPB) ? cnt[tid] : 0;
        int in2 = cc;
        #pragma unroll
        for (int off = 1; off < 32; off <<= 1) {
            const int t = __shfl_up(in2, off);
            if (tid >= off) in2 += t;
        }
        ofs2[tid + 1] = in2;
        if (tid == 0) ofs2[0] = 0;
        cur[tid] = in2 - cc;
    }
    __syncthreads();

    // LDS scatter into dst order + fused ev compute
    for (int i = tid; i < tot; i += 256) {
        const unsigned p = raw[i];
        const int j = (int)(p & 0xffffu) - d0;
        const int pos = atomicAdd(&cur[j], 1);
        srt[pos] = p;
        float v = s_src[p >> 16] + sdl[j];
        v = (v > 0.f) ? v : NEG * v;
        evs[pos] = __expf(v);
    }
    __syncthreads();

    // gather: wave = dst, lane = feature; unroll 8 (8 Whb rows in flight)
    for (int j = wv; j < DPB; j += 4) {
        const int d = d0 + j;
        const int beg = ofs2[j];
        const int end = ofs2[j + 1];
        float acc = 0.f, den = 0.f;
        int i = beg;
        for (; i + 8 <= end; i += 8) {
            int ss[8]; float ee[8], w[8];
            #pragma unroll
            for (int k = 0; k < 8; ++k) {
                ss[k] = (int)(srt[i + k] >> 16);
                ee[k] = evs[i + k];
            }
            #pragma unroll
            for (int k = 0; k < 8; ++k)
                w[k] = __bfloat162float(Whb[(size_t)ss[k] * FOUT + lane]);
            #pragma unroll
            for (int k = 0; k < 8; ++k) {
                acc = fmaf(ee[k], w[k], acc);
                den += ee[k];
            }
        }
        for (; i < end; ++i) {
            const int s0 = (int)(srt[i] >> 16);
            const float e0 = evs[i];
            acc = fmaf(e0, __bfloat162float(Whb[(size_t)s0 * FOUT + lane]), acc);
            den += e0;
        }
        const float r = acc / (den + 1e-16f);
        out[(size_t)d * FOUT + lane] = (r > 0.f) ? r : expm1f(r);
    }
}

extern "C" void kernel_launch(void* const* d_in, const int* in_sizes, int n_in,
                              void* d_out, int out_size, void* d_ws, size_t ws_size,
                              hipStream_t stream)
{
    const float* x     = (const float*)d_in[0];
    const int*   ei    = (const int*)d_in[1];   // [2,E]: src = ei[0..E), dst = ei[E..2E)
    const float* W     = (const float*)d_in[2];
    const float* a_src = (const float*)d_in[3];
    const float* a_dst = (const float*)d_in[4];
    float* out = (float*)d_out;

    // Workspace: Whb 6.4 MB | s_src 200 KB | s_dst 200 KB | gofs 2 MB |
    // gofs_t 2 MB | bdata 4 MB  -> ~14.8 MB. No memsets needed.
    float* ws    = (float*)d_ws;
    __hip_bfloat16* Whb = (__hip_bfloat16*)ws;
    float* s_src = ws + (size_t)NN * FOUT / 2;
    float* s_dst = s_src + NN;
    int*   gofs  = (int*)(s_dst + NN);
    int*   gofs_t = gofs + (size_t)NT * NB;
    unsigned* bdata = (unsigned*)(gofs_t + (size_t)NB * NTP);

    k_front<<<TILE_BLKS + GEMM_BLKS, 512, 0, stream>>>(
        x, W, a_src, a_dst, ei, Whb, s_src, s_dst, bdata, gofs);
    k_transp<<<512, 256, 0, stream>>>(gofs, gofs_t);
    k_sortgather<<<NBUSED, 256, 0, stream>>>(gofs_t, bdata, s_src, s_dst,
                                             Whb, out);
}